// Round 9
// baseline (373.413 us; speedup 1.0000x reference)
//
#include <hip/hip_runtime.h>

#define EPS_F 1e-7f

typedef float f4v __attribute__((ext_vector_type(4)));  // clang-native vec4

constexpr int Bb = 8;
constexpr int Ss = 512;
constexpr int Ff = 128;
constexpr int OUTROW4 = (Ff + Ff * Ff) / 4;  // 4128 float4 per output row

// One query row (b,i) per block; 4096 blocks -> 8 resident blocks/CU so the
// store phase of some blocks always overlaps the compute phase of others.
__global__ __launch_bounds__(256) void attn_fused(const float* __restrict__ x,
                                                  float* __restrict__ out) {
  const int t = threadIdx.x;      // 0..255
  const int bi = blockIdx.x;      // 0..4095
  const int b = bi >> 9;          // batch
  const int i = bi & 511;         // query index

  __shared__ float qrow[Ff];        // 512 B
  __shared__ float e_lds[Ss];       // 2 KB
  __shared__ f4v part[8][Ff / 4];   // 4 KB (8 s-groups x 32 f4)
  __shared__ f4v ctx4[Ff / 4];      // 512 B
  __shared__ float red[4];
  __shared__ float inv_d_s;

  const float* xb = x + (size_t)b * Ss * Ff;

  // ---- stage query row ----
  if (t < Ff / 4) ((f4v*)qrow)[t] = ((const f4v*)(xb + (size_t)i * Ff))[t];
  __syncthreads();

  // ---- phase 1: scores e[s] = exp(x[s].q) for s = t, t+256 ----
  float lsum = 0.f;
  const f4v* q4 = (const f4v*)qrow;
  for (int ss = 0; ss < 2; ++ss) {
    const int s = t + ss * 256;
    const f4v* row = (const f4v*)(xb + (size_t)s * Ff);
    float acc = 0.f;
#pragma unroll 8
    for (int k = 0; k < Ff / 4; ++k) {
      const f4v v = row[k];
      const f4v qv = q4[k];  // LDS broadcast
      acc = fmaf(v.x, qv.x, acc);
      acc = fmaf(v.y, qv.y, acc);
      acc = fmaf(v.z, qv.z, acc);
      acc = fmaf(v.w, qv.w, acc);
    }
    const float ex = expf(acc);  // reference uses plain exp, no max-sub
    e_lds[s] = ex;
    lsum += ex;
  }
  // denominator: wave shuffle-reduce then cross-wave via LDS
  {
    float v = lsum;
#pragma unroll
    for (int off = 32; off > 0; off >>= 1) v += __shfl_down(v, off, 64);
    if ((t & 63) == 0) red[t >> 6] = v;
  }
  __syncthreads();  // e_lds + red visible
  if (t == 0) inv_d_s = 1.0f / (((red[0] + red[1]) + (red[2] + red[3])) + EPS_F);
  // (inv_d_s is consumed only after the next barrier)

  // ---- phase 2: partial ctx over s-group sg = t>>5, feature f4 = t&31 ----
  {
    const int f4 = t & 31, sg = t >> 5;
    const f4v* xcol = (const f4v*)xb;
    const int s0 = sg * 64;
    f4v a = {0.f, 0.f, 0.f, 0.f};
#pragma unroll 4
    for (int s = s0; s < s0 + 64; ++s) {
      const f4v vv = xcol[s * 32 + f4];  // contiguous 512B per 32-lane group
      const float w = e_lds[s];          // broadcast
      a.x = fmaf(w, vv.x, a.x);
      a.y = fmaf(w, vv.y, a.y);
      a.z = fmaf(w, vv.z, a.z);
      a.w = fmaf(w, vv.w, a.w);
    }
    part[sg][f4] = a;
  }
  __syncthreads();  // part + inv_d_s visible
  if (t < 32) {
    f4v a = part[0][t];
#pragma unroll
    for (int g = 1; g < 8; ++g) {
      const f4v p = part[g][t];
      a.x += p.x; a.y += p.y; a.z += p.z; a.w += p.w;
    }
    const float inv = inv_d_s;
    a.x *= inv; a.y *= inv; a.z *= inv; a.w *= inv;
    ctx4[t] = a;
  }
  __syncthreads();

  // ---- phase 3: out row = concat([x_row, tile(ctx,128)]), nt-stores ----
  f4v* out4 = (f4v*)out;
  const size_t rb4 = (size_t)(b * Ss + i) * OUTROW4;
  if (t < 32) {
    __builtin_nontemporal_store(((const f4v*)qrow)[t], &out4[rb4 + t]);
  }
  const f4v cv = ctx4[t & 31];
  f4v* dst = out4 + rb4 + 32;
#pragma unroll
  for (int k = 0; k < 16; ++k) {
    __builtin_nontemporal_store(cv, &dst[t + k * 256]);  // 1 KB/wave, coalesced
  }
}

extern "C" void kernel_launch(void* const* d_in, const int* in_sizes, int n_in,
                              void* d_out, int out_size, void* d_ws, size_t ws_size,
                              hipStream_t stream) {
  const float* x = (const float*)d_in[0];
  float* out = (float*)d_out;
  attn_fused<<<dim3(Bb * Ss), dim3(256), 0, stream>>>(x, out);
}

// Round 12
// 296.390 us; speedup vs baseline: 1.2599x; 1.2599x over previous
//
#include <hip/hip_runtime.h>

#define EPS_F 1e-7f

typedef float f4v __attribute__((ext_vector_type(4)));

constexpr int Bb = 8;
constexpr int Ss = 512;
constexpr int Ff = 128;
constexpr int TQ = 8;                        // q-rows per block (kernel A)
constexpr int OUTROW4 = (Ff + Ff * Ff) / 4;  // 4128 float4 per output row

static __device__ __forceinline__ f4v vfma(float w, f4v v, f4v a) {
  a.x = fmaf(w, v.x, a.x);
  a.y = fmaf(w, v.y, a.y);
  a.z = fmaf(w, v.z, a.z);
  a.w = fmaf(w, v.w, a.w);
  return a;
}

// ---------------- Kernel A: ctx[b][i][:] -> ws (2 MB) ----------------
__global__ __launch_bounds__(256) void attn_ctx(const float* __restrict__ x,
                                                float* __restrict__ ctx) {
  const int t = threadIdx.x;           // 0..255
  const int b = blockIdx.x >> 6;       // batch
  const int i0 = (blockIdx.x & 63) * TQ;

  __shared__ f4v qt4[TQ][Ff / 4];      // 4 KB   query tile
  __shared__ f4v e_t4[Ss][2];          // 16 KB  e transposed: e_t[s][q0..3],[q4..7]
  __shared__ f4v part[8][TQ][Ff / 4];  // 32 KB  [s-group][q][f4] partial ctx
  __shared__ float red[4][TQ];
  __shared__ float inv_d[TQ];

  const float* xb = x + (size_t)b * Ss * Ff;

  // stage 8 q-rows (256 f4v, one per thread)
  ((f4v*)qt4)[t] = ((const f4v*)(xb + (size_t)i0 * Ff))[t];
  __syncthreads();

  // ---- phase 1: thread t owns key rows s=t and s=t+256 ----
  float acc0[TQ], acc1[TQ];
#pragma unroll
  for (int q = 0; q < TQ; ++q) { acc0[q] = 0.f; acc1[q] = 0.f; }
  {
    const f4v* r0 = (const f4v*)(xb + (size_t)t * Ff);
    const f4v* r1 = (const f4v*)(xb + (size_t)(t + 256) * Ff);
#pragma unroll 4
    for (int k = 0; k < Ff / 4; ++k) {
      const f4v v0 = r0[k], v1 = r1[k];
#pragma unroll
      for (int q = 0; q < TQ; ++q) {
        const f4v qv = qt4[q][k];  // LDS broadcast, shared by both rows
        acc0[q] = fmaf(v0.x, qv.x, acc0[q]);
        acc0[q] = fmaf(v0.y, qv.y, acc0[q]);
        acc0[q] = fmaf(v0.z, qv.z, acc0[q]);
        acc0[q] = fmaf(v0.w, qv.w, acc0[q]);
        acc1[q] = fmaf(v1.x, qv.x, acc1[q]);
        acc1[q] = fmaf(v1.y, qv.y, acc1[q]);
        acc1[q] = fmaf(v1.z, qv.z, acc1[q]);
        acc1[q] = fmaf(v1.w, qv.w, acc1[q]);
      }
    }
  }
  float e0[TQ], e1[TQ], ls[TQ];
#pragma unroll
  for (int q = 0; q < TQ; ++q) {
    e0[q] = expf(acc0[q]);  // reference: plain exp, no max-sub
    e1[q] = expf(acc1[q]);
    ls[q] = e0[q] + e1[q];
  }
  e_t4[t][0] = (f4v){e0[0], e0[1], e0[2], e0[3]};
  e_t4[t][1] = (f4v){e0[4], e0[5], e0[6], e0[7]};
  e_t4[t + 256][0] = (f4v){e1[0], e1[1], e1[2], e1[3]};
  e_t4[t + 256][1] = (f4v){e1[4], e1[5], e1[6], e1[7]};
  // denominators: wave butterfly then cross-wave via LDS
#pragma unroll
  for (int q = 0; q < TQ; ++q) {
    float v = ls[q];
#pragma unroll
    for (int off = 32; off > 0; off >>= 1) v += __shfl_down(v, off, 64);
    if ((t & 63) == 0) red[t >> 6][q] = v;
  }
  __syncthreads();  // e_t4 + red visible
  if (t < TQ) {
    inv_d[t] =
        1.0f / (((red[0][t] + red[1][t]) + (red[2][t] + red[3][t])) + EPS_F);
  }

  // ---- phase 2: s-group partials; each x row read ONCE per block ----
  {
    const int f4 = t & 31, sg = t >> 5;
    const f4v* xc = (const f4v*)xb;
    f4v a[TQ];
#pragma unroll
    for (int q = 0; q < TQ; ++q) a[q] = (f4v){0.f, 0.f, 0.f, 0.f};
    const int s0 = sg * 64;
#pragma unroll 2
    for (int s = s0; s < s0 + 64; ++s) {
      const f4v v = xc[s * 32 + f4];     // coalesced 512B per 32-lane group
      const f4v wlo = e_t4[s][0];        // broadcast
      const f4v whi = e_t4[s][1];
      a[0] = vfma(wlo.x, v, a[0]);
      a[1] = vfma(wlo.y, v, a[1]);
      a[2] = vfma(wlo.z, v, a[2]);
      a[3] = vfma(wlo.w, v, a[3]);
      a[4] = vfma(whi.x, v, a[4]);
      a[5] = vfma(whi.y, v, a[5]);
      a[6] = vfma(whi.z, v, a[6]);
      a[7] = vfma(whi.w, v, a[7]);
    }
#pragma unroll
    for (int q = 0; q < TQ; ++q) part[sg][q][f4] = a[q];
  }
  __syncthreads();  // part + inv_d visible

  // ---- reduce 8 partials, scale, store ctx row ----
  {
    const int f4 = t & 31, q = t >> 5;
    f4v c = part[0][q][f4];
#pragma unroll
    for (int g = 1; g < 8; ++g) {
      const f4v p = part[g][q][f4];
      c.x += p.x; c.y += p.y; c.z += p.z; c.w += p.w;
    }
    const float inv = inv_d[q];
    c.x *= inv; c.y *= inv; c.z *= inv; c.w *= inv;
    ((f4v*)ctx)[(size_t)(b * Ss + i0 + q) * (Ff / 4) + f4] = c;
  }
}

// ---------------- Kernel B: pure streaming writer ----------------
__global__ __launch_bounds__(256) void attn_write(const float* __restrict__ x,
                                                  const float* __restrict__ ctx,
                                                  float* __restrict__ out) {
  const int t = threadIdx.x;
  const size_t row = blockIdx.x;  // b*512 + i, 0..4095
  const f4v cv = ((const f4v*)ctx)[row * (Ff / 4) + (t & 31)];  // L2-hot
  f4v* out4 = (f4v*)out;
  const size_t rb4 = row * OUTROW4;
  if (t < 32) {
    __builtin_nontemporal_store(((const f4v*)x)[row * (Ff / 4) + t],
                                &out4[rb4 + t]);  // x part
  }
  f4v* dst = out4 + rb4 + 32;
#pragma unroll
  for (int k = 0; k < 16; ++k) {
    __builtin_nontemporal_store(cv, &dst[t + k * 256]);  // 1 KB/wave stores
  }
}

extern "C" void kernel_launch(void* const* d_in, const int* in_sizes, int n_in,
                              void* d_out, int out_size, void* d_ws, size_t ws_size,
                              hipStream_t stream) {
  const float* x = (const float*)d_in[0];
  float* out = (float*)d_out;
  float* ctx = (float*)d_ws;  // 8*512*128 f32 = 2 MB scratch
  attn_ctx<<<dim3(Bb * (Ss / TQ)), dim3(256), 0, stream>>>(x, ctx);
  attn_write<<<dim3(Bb * Ss), dim3(256), 0, stream>>>(x, ctx, out);
}

// Round 18
// 293.338 us; speedup vs baseline: 1.2730x; 1.0104x over previous
//
#include <hip/hip_runtime.h>

#define EPS_F 1e-7f

typedef float f4v __attribute__((ext_vector_type(4)));

constexpr int Bb = 8;
constexpr int Ss = 512;
constexpr int Ff = 128;
constexpr int TQ = 8;                        // q-rows per block (kernel A)
constexpr int OUTROW4 = (Ff + Ff * Ff) / 4;  // 4128 float4 per output row

static __device__ __forceinline__ f4v vfma(float w, f4v v, f4v a) {
  a.x = fmaf(w, v.x, a.x);
  a.y = fmaf(w, v.y, a.y);
  a.z = fmaf(w, v.z, a.z);
  a.w = fmaf(w, v.w, a.w);
  return a;
}

// ---------------- Kernel A: ctx[b][i][:] -> ws (2 MB) ----------------
__global__ __launch_bounds__(256) void attn_ctx(const float* __restrict__ x,
                                                float* __restrict__ ctx) {
  const int t = threadIdx.x;           // 0..255
  const int b = blockIdx.x >> 6;       // batch
  const int i0 = (blockIdx.x & 63) * TQ;

  __shared__ f4v qt4[TQ][Ff / 4];      // 4 KB   query tile
  __shared__ f4v e_t4[Ss][2];          // 16 KB  e transposed: e_t[s][q0..3],[q4..7]
  __shared__ f4v part[8][TQ][Ff / 4];  // 32 KB  [s-group][q][f4] partial ctx
  __shared__ float red[4][TQ];
  __shared__ float inv_d[TQ];

  const float* xb = x + (size_t)b * Ss * Ff;

  // stage 8 q-rows (256 f4v, one per thread)
  ((f4v*)qt4)[t] = ((const f4v*)(xb + (size_t)i0 * Ff))[t];
  __syncthreads();

  // ---- phase 1: thread t owns key rows s=t and s=t+256 ----
  float acc0[TQ], acc1[TQ];
#pragma unroll
  for (int q = 0; q < TQ; ++q) { acc0[q] = 0.f; acc1[q] = 0.f; }
  {
    const f4v* r0 = (const f4v*)(xb + (size_t)t * Ff);
    const f4v* r1 = (const f4v*)(xb + (size_t)(t + 256) * Ff);
#pragma unroll 4
    for (int k = 0; k < Ff / 4; ++k) {
      const f4v v0 = r0[k], v1 = r1[k];
#pragma unroll
      for (int q = 0; q < TQ; ++q) {
        const f4v qv = qt4[q][k];  // LDS broadcast, shared by both rows
        acc0[q] = fmaf(v0.x, qv.x, acc0[q]);
        acc0[q] = fmaf(v0.y, qv.y, acc0[q]);
        acc0[q] = fmaf(v0.z, qv.z, acc0[q]);
        acc0[q] = fmaf(v0.w, qv.w, acc0[q]);
        acc1[q] = fmaf(v1.x, qv.x, acc1[q]);
        acc1[q] = fmaf(v1.y, qv.y, acc1[q]);
        acc1[q] = fmaf(v1.z, qv.z, acc1[q]);
        acc1[q] = fmaf(v1.w, qv.w, acc1[q]);
      }
    }
  }
  float e0[TQ], e1[TQ], ls[TQ];
#pragma unroll
  for (int q = 0; q < TQ; ++q) {
    e0[q] = expf(acc0[q]);  // reference: plain exp, no max-sub
    e1[q] = expf(acc1[q]);
    ls[q] = e0[q] + e1[q];
  }
  e_t4[t][0] = (f4v){e0[0], e0[1], e0[2], e0[3]};
  e_t4[t][1] = (f4v){e0[4], e0[5], e0[6], e0[7]};
  e_t4[t + 256][0] = (f4v){e1[0], e1[1], e1[2], e1[3]};
  e_t4[t + 256][1] = (f4v){e1[4], e1[5], e1[6], e1[7]};
  // denominators: wave butterfly then cross-wave via LDS
#pragma unroll
  for (int q = 0; q < TQ; ++q) {
    float v = ls[q];
#pragma unroll
    for (int off = 32; off > 0; off >>= 1) v += __shfl_down(v, off, 64);
    if ((t & 63) == 0) red[t >> 6][q] = v;
  }
  __syncthreads();  // e_t4 + red visible
  if (t < TQ) {
    inv_d[t] =
        1.0f / (((red[0][t] + red[1][t]) + (red[2][t] + red[3][t])) + EPS_F);
  }

  // ---- phase 2: s-group partials; each x row read ONCE per block ----
  {
    const int f4 = t & 31, sg = t >> 5;
    const f4v* xc = (const f4v*)xb;
    f4v a[TQ];
#pragma unroll
    for (int q = 0; q < TQ; ++q) a[q] = (f4v){0.f, 0.f, 0.f, 0.f};
    const int s0 = sg * 64;
#pragma unroll 2
    for (int s = s0; s < s0 + 64; ++s) {
      const f4v v = xc[s * 32 + f4];     // coalesced 512B per 32-lane group
      const f4v wlo = e_t4[s][0];        // broadcast
      const f4v whi = e_t4[s][1];
      a[0] = vfma(wlo.x, v, a[0]);
      a[1] = vfma(wlo.y, v, a[1]);
      a[2] = vfma(wlo.z, v, a[2]);
      a[3] = vfma(wlo.w, v, a[3]);
      a[4] = vfma(whi.x, v, a[4]);
      a[5] = vfma(whi.y, v, a[5]);
      a[6] = vfma(whi.z, v, a[6]);
      a[7] = vfma(whi.w, v, a[7]);
    }
#pragma unroll
    for (int q = 0; q < TQ; ++q) part[sg][q][f4] = a[q];
  }
  __syncthreads();  // part + inv_d visible

  // ---- reduce 8 partials, scale, store ctx row ----
  {
    const int f4 = t & 31, q = t >> 5;
    f4v c = part[0][q][f4];
#pragma unroll
    for (int g = 1; g < 8; ++g) {
      const f4v p = part[g][q][f4];
      c.x += p.x; c.y += p.y; c.z += p.z; c.w += p.w;
    }
    const float inv = inv_d[q];
    c.x *= inv; c.y *= inv; c.z *= inv; c.w *= inv;
    ((f4v*)ctx)[(size_t)(b * Ss + i0 + q) * (Ff / 4) + f4] = c;
  }
}

// ---------------- Kernel B: pure streaming writer (PLAIN stores A/B) -------
// R12 experiment: fills prove plain dwordx4 stores sustain 6.3 TB/s on this
// buffer; nt-store throughput was never verified. Single-variable test.
__global__ __launch_bounds__(256) void attn_write(const float* __restrict__ x,
                                                  const float* __restrict__ ctx,
                                                  float* __restrict__ out) {
  const int t = threadIdx.x;
  const size_t row = blockIdx.x;  // b*512 + i, 0..4095
  const f4v cv = ((const f4v*)ctx)[row * (Ff / 4) + (t & 31)];  // L2-hot
  f4v* out4 = (f4v*)out;
  const size_t rb4 = row * OUTROW4;
  if (t < 32) {
    out4[rb4 + t] = ((const f4v*)x)[row * (Ff / 4) + t];  // x part
  }
  f4v* dst = out4 + rb4 + 32;
#pragma unroll
  for (int k = 0; k < 16; ++k) {
    dst[t + k * 256] = cv;  // 1 KB/wave plain stores
  }
}

extern "C" void kernel_launch(void* const* d_in, const int* in_sizes, int n_in,
                              void* d_out, int out_size, void* d_ws, size_t ws_size,
                              hipStream_t stream) {
  const float* x = (const float*)d_in[0];
  float* out = (float*)d_out;
  float* ctx = (float*)d_ws;  // 8*512*128 f32 = 2 MB scratch
  attn_ctx<<<dim3(Bb * (Ss / TQ)), dim3(256), 0, stream>>>(x, ctx);
  attn_write<<<dim3(Bb * Ss), dim3(256), 0, stream>>>(x, ctx, out);
}